// Round 1
// baseline (137.501 us; speedup 1.0000x reference)
//
#include <hip/hip_runtime.h>

#define CC 256
#define EE 128
#define BB 8
#define NN 3136
#define NN4 784
#define TILES 13   // ceil(3136/256)

__device__ __forceinline__ float waveReduceSum(float v) {
    #pragma unroll
    for (int off = 32; off > 0; off >>= 1) v += __shfl_down(v, off, 64);
    return v;
}

// xbar[b*C+c] = mean_i x[b,c,i]
__global__ void k_xbar(const float* __restrict__ x, float* __restrict__ xbar) {
    int row = blockIdx.x;          // b*C + c
    int tid = threadIdx.x;
    const float4* xr = (const float4*)(x + (size_t)row * NN);
    float acc = 0.f;
    for (int i = tid; i < NN4; i += 256) {
        float4 v = xr[i];
        acc += (v.x + v.y) + (v.z + v.w);
    }
    acc = waveReduceSum(acc);
    __shared__ float red[4];
    int wid = tid >> 6, lane = tid & 63;
    if (lane == 0) red[wid] = acc;
    __syncthreads();
    if (tid == 0) xbar[row] = (red[0] + red[1] + red[2] + red[3]) * (1.0f / NN);
}

// per-b: vbar = Wv@xbar + bv ; gb[b,c] = Wexp[c,:]@vbar + bexp[c]
// block 0 additionally: A[c] = sum_e Wcat[e]*Wq[e,c] + Wcat[E+e]*Wk[e,c]
//                       cst  = sum_e Wcat[e]*bq[e]   + Wcat[E+e]*bk[e]
__global__ void k_small(const float* __restrict__ xbar,
                        const float* __restrict__ Wq, const float* __restrict__ bq,
                        const float* __restrict__ Wk, const float* __restrict__ bk,
                        const float* __restrict__ Wv, const float* __restrict__ bv,
                        const float* __restrict__ Wcat,
                        const float* __restrict__ Wexp, const float* __restrict__ bexp,
                        float* __restrict__ gb, float* __restrict__ Aout,
                        float* __restrict__ cst) {
    int b = blockIdx.x, tid = threadIdx.x;
    __shared__ float xb_s[CC];
    __shared__ float vb_s[EE];
    xb_s[tid] = xbar[b * CC + tid];
    __syncthreads();
    if (tid < EE) {
        float acc = bv[tid];
        const float* wr = Wv + tid * CC;
        #pragma unroll 8
        for (int c = 0; c < CC; c++) acc += wr[c] * xb_s[c];
        vb_s[tid] = acc;
    }
    __syncthreads();
    {
        float acc = 0.f;
        const float* we = Wexp + tid * EE;
        #pragma unroll 8
        for (int e = 0; e < EE; e++) acc += we[e] * vb_s[e];
        gb[b * CC + tid] = acc + bexp[tid];
    }
    if (b == 0) {
        float a = 0.f;
        #pragma unroll 4
        for (int e = 0; e < EE; e++)
            a += Wcat[e] * Wq[e * CC + tid] + Wcat[EE + e] * Wk[e * CC + tid];
        Aout[tid] = a;
        if (tid == 0) {
            float s = 0.f;
            for (int e = 0; e < EE; e++)
                s += Wcat[e] * bq[e] + Wcat[EE + e] * bk[e];
            cst[0] = s;
        }
    }
}

// s[b,i] = relu(sum_c A[c]*x[b,c,i] + cst)
__global__ void k_s(const float* __restrict__ x, const float* __restrict__ A,
                    const float* __restrict__ cst, float* __restrict__ s_out) {
    __shared__ float A_s[CC];
    int tid = threadIdx.x;
    A_s[tid] = A[tid];
    __syncthreads();
    int b = blockIdx.x / TILES;
    int it = blockIdx.x - b * TILES;
    int i = it * 256 + tid;
    if (i < NN) {
        const float* xb = x + (size_t)b * CC * NN + i;
        float acc = 0.f;
        #pragma unroll 8
        for (int c = 0; c < CC; c++) acc += A_s[c] * xb[(size_t)c * NN];
        float v = acc + cst[0];
        s_out[b * NN + i] = fmaxf(v, 0.f);
    }
}

// out[b,c,i] = x[b,c,i] + s[b,i]*gb[b,c]   (float4 over i)
__global__ void k_out(const float* __restrict__ x, const float* __restrict__ s,
                      const float* __restrict__ gb, float* __restrict__ out) {
    int idx = blockIdx.x * 256 + threadIdx.x;    // over B*C*N4 float4s
    int row = idx / NN4;                          // b*C + c
    int i4 = idx - row * NN4;
    int b = row >> 8;
    float g = gb[row];
    float4 xv = ((const float4*)x)[idx];
    float4 sv = ((const float4*)(s + (size_t)b * NN))[i4];
    float4 o;
    o.x = fmaf(sv.x, g, xv.x);
    o.y = fmaf(sv.y, g, xv.y);
    o.z = fmaf(sv.z, g, xv.z);
    o.w = fmaf(sv.w, g, xv.w);
    ((float4*)out)[idx] = o;
}

extern "C" void kernel_launch(void* const* d_in, const int* in_sizes, int n_in,
                              void* d_out, int out_size, void* d_ws, size_t ws_size,
                              hipStream_t stream) {
    const float* x    = (const float*)d_in[0];
    const float* Wq   = (const float*)d_in[1];
    const float* bq   = (const float*)d_in[2];
    const float* Wk   = (const float*)d_in[3];
    const float* bk   = (const float*)d_in[4];
    const float* Wv   = (const float*)d_in[5];
    const float* bv   = (const float*)d_in[6];
    const float* Wcat = (const float*)d_in[7];
    const float* Wexp = (const float*)d_in[8];
    const float* bexp = (const float*)d_in[9];
    float* out = (float*)d_out;

    float* ws   = (float*)d_ws;
    float* xbar = ws;                 // 2048
    float* gb   = ws + 2048;          // 2048
    float* A    = ws + 4096;          // 256
    float* cst  = ws + 4352;          // 1 (+pad)
    float* s    = ws + 4368;          // B*N = 25088 (16B-aligned: 4368*4 % 16 == 0)

    k_xbar<<<BB * CC, 256, 0, stream>>>(x, xbar);
    k_small<<<BB, 256, 0, stream>>>(xbar, Wq, bq, Wk, bk, Wv, bv, Wcat, Wexp, bexp,
                                    gb, A, cst);
    k_s<<<BB * TILES, 256, 0, stream>>>(x, A, cst, s);
    k_out<<<(BB * CC * NN4) / 256, 256, 0, stream>>>(x, s, gb, out);
}